// Round 5
// baseline (4953.085 us; speedup 1.0000x reference)
//
#include <hip/hip_runtime.h>

typedef __attribute__((ext_vector_type(8))) short short8;
typedef __attribute__((ext_vector_type(4))) float f32x4;
typedef unsigned short u16;
typedef unsigned int u32;

#define NBLK 64

static __device__ __forceinline__ float sigf(float x){ return 1.0f/(1.0f+expf(-x)); }

static __device__ __forceinline__ u16 f2b(float f){
    u32 u = __float_as_uint(f);
    u += 0x7FFFu + ((u>>16)&1u);   // RNE
    return (u16)(u>>16);
}
static __device__ __forceinline__ float us2f(u16 s){ return __uint_as_float(((u32)s)<<16); }
static __device__ __forceinline__ float b2f_lo(u32 u){ return __uint_as_float(u<<16); }
static __device__ __forceinline__ float b2f_hi(u32 u){ return __uint_as_float(u & 0xffff0000u); }

// Device-scope write-through stores (agent scope, sc1): bypass L2, land in LLC.
static __device__ __forceinline__ void st_wt_u16(u16* p, u16 v) {
    asm volatile("global_store_short %0, %1, off sc1" :: "v"(p), "v"((u32)v) : "memory");
}
static __device__ __forceinline__ void st_wt_u32(u32* p, u32 v) {
    asm volatile("global_store_dword %0, %1, off sc1" :: "v"(p), "v"(v) : "memory");
}
static __device__ __forceinline__ void st_wt_f32(float* p, float v) {
    asm volatile("global_store_dword %0, %1, off sc1" :: "v"(p), "v"(v) : "memory");
}
// Coherent (bypass L1+L2) load for flag polling.
static __device__ __forceinline__ u32 ld_cv(const u32* p){
    u32 v;
    asm volatile("global_load_dword %0, %1, off sc0 sc1\ns_waitcnt vmcnt(0)"
                 : "=v"(v) : "v"(p) : "memory");
    return v;
}

// Flag-based grid barrier: NO atomic RMWs (same-line LLC atomics serialize at
// ~230ns each -> 15us/barrier at 64 blocks, measured r2-r4).
//  - each non-root block sc1-stores 1 to its own per-barrier flag word
//  - root block wave0: lane i polls block i's flag, then lane0 stores release
//  - others poll the per-barrier release word (plain reads, no serialization)
// Single-use flag addresses per barrier; zeroed by k_zero before k_seq.
static __device__ __forceinline__ void gbar(u32* arrive, u32* release, int bi) {
    __syncthreads();   // drains vmcnt: all data stores of this block completed
    if (threadIdx.x < 64) {
        if (blockIdx.x == 0) {
            if (threadIdx.x > 0) {
                const u32* p = arrive + (size_t)bi*64 + threadIdx.x;
                while (ld_cv(p) == 0) __builtin_amdgcn_s_sleep(1);
            }
            if (threadIdx.x == 0) st_wt_u32(release + bi, 1u);
        } else if (threadIdx.x == 0) {
            st_wt_u32(arrive + (size_t)bi*64 + blockIdx.x, 1u);
            const u32* p = release + bi;
            while (ld_cv(p) == 0) __builtin_amdgcn_s_sleep(1);
        }
    }
    __syncthreads();
}

// ---------------- utility / conversion kernels ----------------

__global__ __launch_bounds__(256) void k_zero(float* __restrict__ p, long n) {
    for (long i = (long)blockIdx.x*256 + threadIdx.x; i < n; i += (long)gridDim.x*256) p[i] = 0.0f;
}

__global__ __launch_bounds__(256) void k_f2b(const float4* __restrict__ src,
                                             ushort4* __restrict__ dst, long n4) {
    for (long i = (long)blockIdx.x*256 + threadIdx.x; i < n4; i += (long)gridDim.x*256) {
        float4 v = src[i];
        ushort4 u;
        u.x = f2b(v.x); u.y = f2b(v.y); u.z = f2b(v.z); u.w = f2b(v.w);
        dst[i] = u;
    }
}

// WencB[(j*4+q)*512 + k] = bf16(whh[(q*512+j)*512 + k])
__global__ __launch_bounds__(256) void k_wenc(const float* __restrict__ whh, u16* __restrict__ dst) {
    int i = blockIdx.x*256 + threadIdx.x;           // 1,048,576
    int n = i >> 9, k = i & 511;
    int j = n >> 2, q = n & 3;
    dst[i] = f2b(whh[(size_t)(q*512 + j)*512 + k]);
}

// awiTB[kcol*1024 + n] = bf16(awi[n*1024 + kcol])
__global__ __launch_bounds__(256) void k_awiT(const float* __restrict__ awi, u16* __restrict__ dst) {
    int i = blockIdx.x*256 + threadIdx.x;           // 1,048,576
    int kcol = i >> 10, n = i & 1023;
    dst[i] = f2b(awi[(size_t)n*1024 + kcol]);
}

// WdecB[(j*4+q)*2048 + k] = bf16( k<1024 ? dwih[(q*1024+j)*1324+k] : dwhh[(q*1024+j)*1024+k-1024] )
__global__ __launch_bounds__(256) void k_wdec(const float* __restrict__ dwih,
                                              const float* __restrict__ dwhh,
                                              u16* __restrict__ dst) {
    for (long i = (long)blockIdx.x*256 + threadIdx.x; i < 8388608L; i += (long)gridDim.x*256) {
        int n = (int)(i >> 11), k = (int)(i & 2047);
        int j = n >> 2, q = n & 3;
        float v = (k < 1024) ? dwih[(size_t)(q*1024 + j)*1324 + k]
                             : dwhh[(size_t)(q*1024 + j)*1024 + (k - 1024)];
        dst[i] = f2b(v);
    }
}

// X = gather(table, idx) @ W[:, koff:koff+300]^T + bias, stored bf16, gate-packed col = (jj&jmask)*4 | (jj>>jshift)
__global__ __launch_bounds__(256) void k_xw(const float* __restrict__ table,
                                            const int* __restrict__ idx,
                                            const float* __restrict__ W,
                                            int wstride, int koff,
                                            const float* __restrict__ bias,
                                            u16* __restrict__ outU, int N,
                                            int jmask, int jshift) {
    __shared__ float Xs[32][300];
    int m0 = blockIdx.y * 32;
    int j0 = blockIdx.x * 64;
    for (int i = threadIdx.x; i < 32*300; i += 256) {
        int r = i/300, c = i - r*300;
        Xs[r][c] = table[(size_t)idx[m0+r]*300 + c];
    }
    __syncthreads();
    int tx = threadIdx.x & 63, ty = threadIdx.x >> 6;
    int jj = j0 + tx;
    const float* wr = W + (size_t)jj*wstride + koff;
    float acc[8] = {0,0,0,0,0,0,0,0};
    for (int k = 0; k < 300; ++k) {
        float w = wr[k];
#pragma unroll
        for (int mi = 0; mi < 8; ++mi) acc[mi] += Xs[ty*8+mi][k] * w;
    }
    float bv = bias[jj];
    int col = ((jj & jmask) << 2) | (jj >> jshift);
#pragma unroll
    for (int mi = 0; mi < 8; ++mi)
        outU[(size_t)(m0 + ty*8 + mi)*N + col] = f2b(acc[mi] + bv);
}

// ---------------- persistent recurrence kernel ----------------
// 64 blocks x 512 threads (8 waves). All matmuls via MFMA in bf16.
// Fresh-address discipline + WT stores: every cross-block datum has a unique
// per-step slot and is stored with sc1 (direct to LLC).
__global__ __launch_bounds__(512) void k_seq(
    const u16* __restrict__ Xf, const u16* __restrict__ Xb, const u16* __restrict__ Xe,
    const u16* __restrict__ WencB, const u16* __restrict__ awiTB,
    const u16* __restrict__ awoB, const u16* __restrict__ WdecB,
    u16* __restrict__ encBX,   // 65 slots [32][1024]: slot 0 zeros, slot s+1 = enc_out[s] (bf16)
    u16* __restrict__ Hd,      // 65 slots [32][1024]: slot 0 init hidden, slot t+1 = h after dec step t, slot 64 zeros
    u16* __restrict__ Stb,     // 63 slots [32][1024] s_tilde
    u16* __restrict__ Ctb,     // 63 slots [32][1024] c_t
    u16* __restrict__ encPB,   // [2048][1024] enc_out @ attn_wi (bf16)
    float* __restrict__ cfin,  // [2][32][512] final encoder c
    u32* arrive, u32* release)
{
    __shared__ float SH[2304];
    const int tid = threadIdx.x;
    const int bid = blockIdx.x;
    const int wv = tid >> 6, lane = tid & 63;
    const int gwave = bid*8 + wv;
    const int lr = lane & 15, lk8 = (lane >> 4)*8;
    const int b_l = lane & 15, jjq = lane >> 4;
    const int gt = bid*512 + tid;
    int bi = 0;

    // ---- P0: zero encBX slot 0 ----
    if (gt < 16384) st_wt_u32((u32*)encBX + gt, 0u);
    gbar(arrive, release, bi++);

    // ---- encoder: 64 steps ----
    {
        const int dir = gwave >> 8;
        const int mt = (gwave >> 7) & 1;
        const int nt = gwave & 127;
        const int m0 = mt*16, n0 = nt*16;
        const u16* Bw = WencB + (size_t)dir*1048576 + (size_t)(n0+lr)*512 + lk8;
        const u16* Xd = dir ? Xb : Xf;
        float* T = SH + wv*272;
        const int bb = m0 + b_l;
        const int j = nt*4 + jjq;
        float creg = 0.f;
        for (int t = 0; t < 64; ++t) {
            const int rslot = (t==0) ? 0 : (dir ? (65-t) : t);
            const u16* Ah = encBX + (size_t)rslot*32768 + (size_t)(m0+lr)*1024 + dir*512 + lk8;
            f32x4 acc = {0.f,0.f,0.f,0.f};
#pragma unroll
            for (int i = 0; i < 16; ++i) {
                short8 av = *(const short8*)(Ah + i*32);
                short8 bv = *(const short8*)(Bw + i*32);
                acc = __builtin_amdgcn_mfma_f32_16x16x32_bf16(av, bv, acc, 0, 0, 0);
            }
            {
                const int rb = (lane>>4)*4;
#pragma unroll
                for (int r = 0; r < 4; ++r) T[(rb+r)*17 + (lane&15)] = acc[r];
            }
            __builtin_amdgcn_sched_barrier(0);
            const int s = dir ? (63-t) : t;
            ushort4 xr = *(const ushort4*)(Xd + (size_t)(s*32+bb)*2048 + n0 + jjq*4);
            float gi = T[b_l*17 + jjq*4 + 0] + us2f(xr.x);
            float gf = T[b_l*17 + jjq*4 + 1] + us2f(xr.y);
            float gg = T[b_l*17 + jjq*4 + 2] + us2f(xr.z);
            float go = T[b_l*17 + jjq*4 + 3] + us2f(xr.w);
            float c2 = sigf(gf)*creg + sigf(gi)*tanhf(gg);
            float h2 = sigf(go)*tanhf(c2);
            creg = c2;
            st_wt_u16(encBX + (size_t)(s+1)*32768 + (size_t)bb*1024 + dir*512 + j, f2b(h2));
            gbar(arrive, release, bi++);
        }
        st_wt_f32(cfin + dir*16384 + bb*512 + j, creg);
    }

    // ---- pack: Hd[0] = interleaved final h; zero Hd[64] (generator pad) ----
    {
        int b = gt >> 10, jj2 = gt & 1023;
        int d = jj2 & 1, k = jj2 >> 1;
        st_wt_u16(Hd + (size_t)b*1024 + jj2,
                  encBX[(size_t)(d ? 1 : 64)*32768 + (size_t)b*1024 + d*512 + k]);
        st_wt_u16(Hd + (size_t)64*32768 + gt, 0);
    }
    gbar(arrive, release, bi++);

    // ---- encP = enc_out @ attn_wi  (M=2048, N=1024, K=1024) ----
    {
        const u16* Abase = encBX + 32768;
        for (int ii = 0; ii < 16; ++ii) {
            int id = gwave*16 + ii;
            int mt2 = id >> 6, nt2 = id & 63;
            int m0 = mt2*16, n0 = nt2*16;
            const u16* Ar = Abase + (size_t)(m0+lr)*1024 + lk8;
            const u16* Br = awiTB + (size_t)(n0+lr)*1024 + lk8;
            f32x4 acc = {0.f,0.f,0.f,0.f};
#pragma unroll 8
            for (int i = 0; i < 32; ++i) {
                short8 av = *(const short8*)(Ar + i*32);
                short8 bv = *(const short8*)(Br + i*32);
                acc = __builtin_amdgcn_mfma_f32_16x16x32_bf16(av, bv, acc, 0, 0, 0);
            }
            int col = n0 + (lane&15);
            int rb = m0 + (lane>>4)*4;
#pragma unroll
            for (int r = 0; r < 4; ++r)
                st_wt_u16(encPB + (size_t)(rb+r)*1024 + col, f2b(acc[r]));
        }
    }
    gbar(arrive, release, bi++);

    // ---- decoder: c-init from cfin (c lives in registers) ----
    const int nt4 = gwave >> 1, mt4 = gwave & 1;
    const int n0d = nt4*16, m0d = mt4*16;
    const int bbd = m0d + b_l;
    const int jd = nt4*4 + jjq;
    float cdec = cfin[(jd&1)*16384 + bbd*512 + (jd>>1)];

    // ---- decoder: 63 steps x {P2 attn, P3 c_t, P4 gates+cell} ----
    for (int t = 0; t < 63; ++t) {
        // P2: scores = encP . h ; softmax(S=64); s_tilde = sum_s p_s * enc_out[s]
        if (bid < 32) {
            const int bbb = bid;
            float* hsh = SH; float* red = SH + 1024; float* sc = SH + 1536;
            {
                u32 u = ((const u32*)Hd)[(size_t)t*16384 + bbb*512 + tid];
                hsh[2*tid]   = b2f_lo(u);
                hsh[2*tid+1] = b2f_hi(u);
            }
            __syncthreads();
            {
                int s = tid >> 3, p = tid & 7;
                const uint4* ep = (const uint4*)(encPB + (size_t)(s*32+bbb)*1024 + p*128);
                const float* hk = hsh + p*128;
                float a0=0,a1=0,a2=0,a3=0;
#pragma unroll 4
                for (int q8 = 0; q8 < 16; ++q8) {
                    uint4 u = ep[q8];
                    a0 += b2f_lo(u.x)*hk[q8*8+0] + b2f_hi(u.x)*hk[q8*8+1];
                    a1 += b2f_lo(u.y)*hk[q8*8+2] + b2f_hi(u.y)*hk[q8*8+3];
                    a2 += b2f_lo(u.z)*hk[q8*8+4] + b2f_hi(u.z)*hk[q8*8+5];
                    a3 += b2f_lo(u.w)*hk[q8*8+6] + b2f_hi(u.w)*hk[q8*8+7];
                }
                red[tid] = (a0+a1)+(a2+a3);
            }
            __syncthreads();
            if (tid < 64) {
                float v = 0;
#pragma unroll
                for (int pp = 0; pp < 8; ++pp) v += red[tid*8+pp];
                float m = v;
                for (int off = 32; off; off >>= 1) m = fmaxf(m, __shfl_xor(m, off));
                float e = expf(v - m);
                float ss = e;
                for (int off = 32; off; off >>= 1) ss += __shfl_xor(ss, off);
                sc[tid] = e / ss;
            }
            __syncthreads();
            {
                float st0 = 0, st1 = 0;
                const u32* eb = (const u32*)encBX + 16384 + bbb*512 + tid;  // slot s2+1
#pragma unroll 4
                for (int s2 = 0; s2 < 64; ++s2) {
                    u32 u = eb[(size_t)s2*16384];
                    float w = sc[s2];
                    st0 += w*b2f_lo(u); st1 += w*b2f_hi(u);
                }
                u32 pk = (u32)f2b(st0) | ((u32)f2b(st1) << 16);
                st_wt_u32((u32*)Stb + (size_t)t*16384 + bbb*512 + tid, pk);
            }
        }
        gbar(arrive, release, bi++);

        // P3: c_t = tanh([s_tilde, h] @ awo^T)  (K split 4 ways across waves)
        {
            const int nt3 = bid;
            const int mt3 = wv >> 2, kq = wv & 3;
            const int m0 = mt3*16, n0 = nt3*16;
            const u16* Br = awoB + (size_t)(n0+lr)*2048 + kq*512 + lk8;
            const u16* As  = Stb + (size_t)t*32768 + (size_t)(m0+lr)*1024 + kq*512 + lk8;
            const u16* Ah2 = Hd  + (size_t)t*32768 + (size_t)(m0+lr)*1024 + (kq-2)*512 + lk8;
            const u16* Ar = (kq < 2) ? As : Ah2;
            f32x4 acc = {0.f,0.f,0.f,0.f};
#pragma unroll 4
            for (int i = 0; i < 16; ++i) {
                short8 av = *(const short8*)(Ar + i*32);
                short8 bv = *(const short8*)(Br + i*32);
                acc = __builtin_amdgcn_mfma_f32_16x16x32_bf16(av, bv, acc, 0, 0, 0);
            }
            float* PH = SH + wv*256;
#pragma unroll
            for (int r = 0; r < 4; ++r) PH[lane*4 + r] = acc[r];
            __syncthreads();
            if (kq == 0) {
#pragma unroll
                for (int r = 0; r < 4; ++r) {
                    float sum = SH[wv*256 + lane*4 + r] + SH[(wv+1)*256 + lane*4 + r]
                              + SH[(wv+2)*256 + lane*4 + r] + SH[(wv+3)*256 + lane*4 + r];
                    int bq = m0 + (lane>>4)*4 + r;
                    st_wt_u16(Ctb + (size_t)t*32768 + (size_t)bq*1024 + n0 + (lane&15),
                              f2b(tanhf(sum)));
                }
            }
        }
        gbar(arrive, release, bi++);

        // P4: gates = [c_t, h] @ Wdec^T + Xe ; cell update; h -> Hd[t+1]
        {
            const u16* Br  = WdecB + (size_t)(n0d+lr)*2048 + lk8;
            const u16* Ac  = Ctb + (size_t)t*32768 + (size_t)(m0d+lr)*1024 + lk8;
            const u16* Ah3 = Hd  + (size_t)t*32768 + (size_t)(m0d+lr)*1024 + lk8;
            f32x4 acc = {0.f,0.f,0.f,0.f};
#pragma unroll 4
            for (int i = 0; i < 32; ++i) {
                short8 av = *(const short8*)(Ac + i*32);
                short8 bv = *(const short8*)(Br + i*32);
                acc = __builtin_amdgcn_mfma_f32_16x16x32_bf16(av, bv, acc, 0, 0, 0);
            }
#pragma unroll 4
            for (int i = 0; i < 32; ++i) {
                short8 av = *(const short8*)(Ah3 + i*32);
                short8 bv = *(const short8*)(Br + 1024 + i*32);
                acc = __builtin_amdgcn_mfma_f32_16x16x32_bf16(av, bv, acc, 0, 0, 0);
            }
            float* T = SH + wv*272;
            {
                const int rb = (lane>>4)*4;
#pragma unroll
                for (int r = 0; r < 4; ++r) T[(rb+r)*17 + (lane&15)] = acc[r];
            }
            __builtin_amdgcn_sched_barrier(0);
            ushort4 xr = *(const ushort4*)(Xe + (size_t)(t*32+bbd)*4096 + n0d + jjq*4);
            float gi = T[b_l*17 + jjq*4 + 0] + us2f(xr.x);
            float gf = T[b_l*17 + jjq*4 + 1] + us2f(xr.y);
            float gg = T[b_l*17 + jjq*4 + 2] + us2f(xr.z);
            float go = T[b_l*17 + jjq*4 + 3] + us2f(xr.w);
            float c2 = sigf(gf)*cdec + sigf(gi)*tanhf(gg);
            float h2 = sigf(go)*tanhf(c2);
            cdec = c2;
            st_wt_u16(Hd + (size_t)(t+1)*32768 + (size_t)bbd*1024 + jd, f2b(h2));
        }
        gbar(arrive, release, bi++);
    }
}

// ---------------- generator GEMM (bf16 MFMA) ----------------
__global__ __launch_bounds__(256) void k_gemm_gen(const short* __restrict__ A,
                                                  const short* __restrict__ B,
                                                  const float* __restrict__ genb,
                                                  float* __restrict__ out) {
    int wave = threadIdx.x >> 6;
    int lane = threadIdx.x & 63;
    int tile = blockIdx.x * 4 + wave;  // 16000 tiles = 32 m x 500 n
    int mt = tile & 31;
    int nt = tile >> 5;
    int m0 = mt*64, n0 = nt*64;
    int lr = lane & 15;
    int lk = (lane >> 4)*8;
    f32x4 acc[4][4] = {};
    for (int k0 = 0; k0 < 1024; k0 += 32) {
        short8 a[4], bfr[4];
#pragma unroll
        for (int mi = 0; mi < 4; ++mi)
            a[mi] = *(const short8*)(A + (long)(m0 + mi*16 + lr)*1024 + k0 + lk);
#pragma unroll
        for (int ni = 0; ni < 4; ++ni)
            bfr[ni] = *(const short8*)(B + (long)(n0 + ni*16 + lr)*1024 + k0 + lk);
#pragma unroll
        for (int mi = 0; mi < 4; ++mi)
#pragma unroll
            for (int ni = 0; ni < 4; ++ni)
                acc[mi][ni] = __builtin_amdgcn_mfma_f32_16x16x32_bf16(a[mi], bfr[ni], acc[mi][ni], 0, 0, 0);
    }
    int dcol = lane & 15;
    int drow = (lane >> 4)*4;
#pragma unroll
    for (int mi = 0; mi < 4; ++mi) {
        int mbase = m0 + mi*16 + drow;
#pragma unroll
        for (int ni = 0; ni < 4; ++ni) {
            int n = n0 + ni*16 + dcol;
            float bv = genb[n];
            f32x4 v = acc[mi][ni];
#pragma unroll
            for (int r = 0; r < 4; ++r) {
                int m = mbase + r;
                if (m < 2016) out[(long)(m + 32)*32000 + n] = v[r] + bv;
            }
        }
    }
}

// in-place log-softmax on d_out rows 32..2047
__global__ __launch_bounds__(256) void k_lsm(float* __restrict__ out) {
    long row = 32 + blockIdx.x;
    float* p = out + row*32000L;
    float4* p4 = (float4*)p;
    int tid = threadIdx.x;
    __shared__ float sm[4];
    __shared__ float ss[4];
    float m = -1e30f;
    for (int i = tid; i < 8000; i += 256) {
        float4 v = p4[i];
        m = fmaxf(m, fmaxf(fmaxf(v.x, v.y), fmaxf(v.z, v.w)));
    }
    for (int off = 32; off; off >>= 1) m = fmaxf(m, __shfl_xor(m, off));
    if ((tid & 63) == 0) sm[tid >> 6] = m;
    __syncthreads();
    m = fmaxf(fmaxf(sm[0], sm[1]), fmaxf(sm[2], sm[3]));
    float s = 0;
    for (int i = tid; i < 8000; i += 256) {
        float4 v = p4[i];
        s += expf(v.x - m) + expf(v.y - m) + expf(v.z - m) + expf(v.w - m);
    }
    for (int off = 32; off; off >>= 1) s += __shfl_xor(s, off);
    if ((tid & 63) == 0) ss[tid >> 6] = s;
    __syncthreads();
    s = ss[0] + ss[1] + ss[2] + ss[3];
    float lse = m + logf(s);
    for (int i = tid; i < 8000; i += 256) {
        float4 v = p4[i];
        v.x -= lse; v.y -= lse; v.z -= lse; v.w -= lse;
        p4[i] = v;
    }
}

// ---------------- launch ----------------

extern "C" void kernel_launch(void* const* d_in, const int* in_sizes, int n_in,
                              void* d_out, int out_size, void* d_ws, size_t ws_size,
                              hipStream_t stream) {
    const float* eemb  = (const float*)d_in[0];
    const float* ewihf = (const float*)d_in[1];
    const float* ewhhf = (const float*)d_in[2];
    const float* ebf   = (const float*)d_in[3];
    const float* ewihb = (const float*)d_in[4];
    const float* ewhhb = (const float*)d_in[5];
    const float* ebb   = (const float*)d_in[6];
    const float* awi   = (const float*)d_in[7];
    const float* awo   = (const float*)d_in[8];
    const float* dwih  = (const float*)d_in[9];
    const float* dwhh  = (const float*)d_in[10];
    const float* db    = (const float*)d_in[11];
    const float* demb  = (const float*)d_in[12];
    const float* genw  = (const float*)d_in[13];
    const float* genb  = (const float*)d_in[14];
    const int* srci    = (const int*)d_in[15];
    const int* trgi    = (const int*)d_in[16];
    float* out = (float*)d_out;

    float* F = (float*)d_ws;
    u32*   arrive  = (u32*)F;              // 256*64 u32   [0,16384)
    u32*   release = (u32*)F + 16384;      // 256 u32      [16384,16640)
    float* cfin = F + 16640;               // 32768 floats [16640,49408)
    u16*   U    = (u16*)(F + 49408);       // bf16 region

    u16* Xf_    = U;                       // 2048x2048
    u16* Xb_    = U + 4194304u;            // 2048x2048
    u16* Xe_    = U + 8388608u;            // 2016x4096
    u16* WencB  = U + 16646144u;           // 2 x 2048x512
    u16* awiTB  = U + 18743296u;           // 1024x1024
    u16* awoB   = U + 19791872u;           // 1024x2048
    u16* WdecB  = U + 21889024u;           // 4096x2048
    u16* genw_b = U + 30277632u;           // 32000x1024
    u16* encBX  = U + 63045632u;           // 65 x 32x1024
    u16* Hd     = U + 65175552u;           // 65 x 32x1024
    u16* Stb    = U + 67305472u;           // 63 x 32x1024
    u16* Ctb    = U + 69369856u;           // 63 x 32x1024
    u16* encPB  = U + 71434240u;           // 2048x1024

    // barrier flags + t=0 output rows
    k_zero<<<65, 256, 0, stream>>>(F, 16640);          // arrive + release flags
    k_zero<<<2048, 256, 0, stream>>>(out, 1024000L);

    // input projections (gathered embedding @ W_ih^T + b), bf16 gate-packed
    k_xw<<<dim3(32, 64), 256, 0, stream>>>(eemb, srci, ewihf, 300, 0, ebf, Xf_, 2048, 511, 9);
    k_xw<<<dim3(32, 64), 256, 0, stream>>>(eemb, srci, ewihb, 300, 0, ebb, Xb_, 2048, 511, 9);
    k_xw<<<dim3(64, 63), 256, 0, stream>>>(demb, trgi, dwih, 1324, 1024, db, Xe_, 4096, 1023, 10);

    // weight conversions to bf16
    k_wenc<<<4096, 256, 0, stream>>>(ewhhf, WencB);
    k_wenc<<<4096, 256, 0, stream>>>(ewhhb, WencB + 1048576u);
    k_awiT<<<4096, 256, 0, stream>>>(awi, awiTB);
    k_f2b<<<2048, 256, 0, stream>>>((const float4*)awo, (ushort4*)awoB, 524288L);
    k_wdec<<<8192, 256, 0, stream>>>(dwih, dwhh, WdecB);
    k_f2b<<<8192, 256, 0, stream>>>((const float4*)genw, (ushort4*)genw_b, 8192000L);

    // persistent encoder + decoder
    k_seq<<<NBLK, 512, 0, stream>>>(Xf_, Xb_, Xe_, WencB, awiTB, awoB, WdecB,
                                    encBX, Hd, Stb, Ctb, encPB, cfin, arrive, release);

    // batched generator + log-softmax
    k_gemm_gen<<<4000, 256, 0, stream>>>((const short*)(Hd + 32768u), (const short*)genw_b, genb, out);
    k_lsm<<<2016, 256, 0, stream>>>(out);
}